// Round 16
// baseline (208.653 us; speedup 1.0000x reference)
//
#include <hip/hip_runtime.h>

// GraphConv: out[t] += input[s] * (esgn*enorm), 3.2M edges, 100K nodes, D=32 fp32.
// Round 27: R26 landed (201.4 -> 198.2, bscan folded; gap value measured ~6-8us
// not 13). Two further deltas with independent counter signatures:
//   (a) scan1 folded into scatter: each block row-sums the L2-resident 1MB cnt
//       matrix (256 coalesced iterations, ~2-4us), capturing my=run at g'==g;
//       block 0 writes tot for accum. scan1 kernel + gap + pref array deleted.
//   (b) bucket_accum gather unroll 4 -> 8 deep (latency-bound section: HBM 35%,
//       VALU 12%; mean run 32/node). VGPR ~20 -> ~40, under the 64 ceiling.
// Pipeline (3 kernels): hist -> scatter(+matrix-sum/scan) -> accum(+local bscan).

#define G    256          // edge chunks / scatter blocks
#define KMAX 1024         // max buckets (span 128 -> n_nodes <= 131072)
#define SPAN_SHIFT 7
#define SPAN 128
#define CAP  6144         // bucket_accum LDS record capacity (48KB)
#define NB   256

// Per-chunk histogram: cnt[g*KMAX + b]. Coalesced matrix write, no atomics
// beyond LDS. (Verified R18.)
__global__ __launch_bounds__(1024) void hist_kernel(
    const int* __restrict__ tidx, int* __restrict__ cnt,
    int n_edges, int epb, int vec)
{
    __shared__ int lh[KMAX];
    int g = blockIdx.x, t = threadIdx.x;
    lh[t] = 0;
    __syncthreads();
    int beg = g * epb;
    int lim = beg + epb; if (lim > n_edges) lim = n_edges;
    if (vec) {
        int nq = (lim > beg) ? ((lim - beg) >> 2) : 0;
        for (int q = t; q < nq; q += 1024) {
            int4 tn = *(const int4*)(tidx + beg + q * 4);
            atomicAdd(&lh[tn.x >> SPAN_SHIFT], 1);
            atomicAdd(&lh[tn.y >> SPAN_SHIFT], 1);
            atomicAdd(&lh[tn.z >> SPAN_SHIFT], 1);
            atomicAdd(&lh[tn.w >> SPAN_SHIFT], 1);
        }
        for (int e = beg + (nq << 2) + t; e < lim; e += 1024)
            atomicAdd(&lh[tidx[e] >> SPAN_SHIFT], 1);
    } else {
        for (int e = beg + t; e < lim; e += 1024)
            atomicAdd(&lh[tidx[e] >> SPAN_SHIFT], 1);
    }
    __syncthreads();
    cnt[g * KMAX + t] = lh[t];
}

// Deterministic scatter, R27: per-block matrix row-sum over cnt gives this
// block's pref (my) and all bucket totals; LDS scan of totals gives bases.
// Block 0 publishes tot for bucket_accum. No scan1 kernel, no pref array.
__global__ __launch_bounds__(1024) void scatter_kernel(
    const int* __restrict__ sidx, const int* __restrict__ tidx,
    const float* __restrict__ enorm, const float* __restrict__ esgn,
    const int* __restrict__ cnt, int* __restrict__ tot,
    int2* __restrict__ recs, int n_edges, int epb, int vec)
{
    __shared__ int gbase[KMAX];
    __shared__ int lh[KMAX];
    __shared__ int part[KMAX];
    int g = blockIdx.x, t = threadIdx.x;

    // row-sum of cnt over chunks; capture exclusive prefix at g'==g
    int run = 0, my = 0;
    for (int gp = 0; gp < G; ++gp) {
        if (gp == g) my = run;
        run += cnt[gp * KMAX + t];
    }
    if (g == 0) tot[t] = run;            // for bucket_accum (runs after us)
    part[t] = run;
    __syncthreads();
    // exclusive scan of totals -> bucket bases
    for (int off = 1; off < KMAX; off <<= 1) {
        int v = (t >= off) ? part[t - off] : 0;
        __syncthreads();
        part[t] += v;
        __syncthreads();
    }
    gbase[t] = (part[t] - run) + my;
    lh[t] = 0;
    __syncthreads();

    int beg = g * epb;
    int lim = beg + epb; if (lim > n_edges) lim = n_edges;

    #define SCAT_EDGE(tn_, sn_, w_) {                                        \
        int b_ = (tn_) >> SPAN_SHIFT;                                        \
        int rank_ = atomicAdd(&lh[b_], 1);                                   \
        unsigned rec_ = ((unsigned)(sn_) << SPAN_SHIFT) |                    \
                        (unsigned)((tn_) & (SPAN - 1));                      \
        recs[gbase[b_] + rank_] = make_int2((int)rec_, __float_as_int(w_)); }

    if (vec) {
        int nq = (lim > beg) ? ((lim - beg) >> 2) : 0;
        for (int q = t; q < nq; q += 1024) {
            int e = beg + q * 4;
            int4   tn = *(const int4*)(tidx + e);
            int4   sn = *(const int4*)(sidx + e);
            float4 nw = *(const float4*)(enorm + e);
            float4 sw = *(const float4*)(esgn + e);
            SCAT_EDGE(tn.x, sn.x, nw.x * sw.x);
            SCAT_EDGE(tn.y, sn.y, nw.y * sw.y);
            SCAT_EDGE(tn.z, sn.z, nw.z * sw.z);
            SCAT_EDGE(tn.w, sn.w, nw.w * sw.w);
        }
        for (int e = beg + (nq << 2) + t; e < lim; e += 1024) {
            int tn = tidx[e]; int sn = sidx[e];
            float w = enorm[e] * esgn[e];
            SCAT_EDGE(tn, sn, w);
        }
    } else {
        for (int e = beg + t; e < lim; e += 1024) {
            int tn = tidx[e]; int sn = sidx[e];
            float w = enorm[e] * esgn[e];
            SCAT_EDGE(tn, sn, w);
        }
    }
    #undef SCAT_EDGE
}

// Fused node-sort + accumulate, one block per bucket (128 nodes).
// R27: gather unroll deepened 4 -> 8. Bucket range from local scan of tot.
__global__ __launch_bounds__(1024) void bucket_accum(
    const float* __restrict__ input, const int2* __restrict__ recs,
    const int* __restrict__ tot, float* __restrict__ out, int n_nodes)
{
    __shared__ int2 srec[CAP];             // 48 KB
    __shared__ int part[KMAX];             // 4 KB (scan prologue)
    __shared__ int lcnt[SPAN];
    __shared__ int lbeg[SPAN];
    __shared__ int lcur[SPAN];
    __shared__ int sb[2];
    int b = blockIdx.x;
    int t = threadIdx.x;

    // local exclusive scan of tot -> this bucket's [bstart, bend)
    int c = tot[t];
    part[t] = c;
    __syncthreads();
    for (int off = 1; off < KMAX; off <<= 1) {
        int v = (t >= off) ? part[t - off] : 0;
        __syncthreads();
        part[t] += v;
        __syncthreads();
    }
    if (t == b) { sb[0] = part[t] - c; sb[1] = part[t]; }
    __syncthreads();
    int bstart = sb[0], bend = sb[1];
    int base_node = b << SPAN_SHIFT;

    if (bend - bstart <= CAP) {
        if (t < SPAN) lcnt[t] = 0;
        __syncthreads();
        for (int i = bstart + t; i < bend; i += 1024)
            atomicAdd(&lcnt[recs[i].x & (SPAN - 1)], 1);
        __syncthreads();
        int cc = (t < SPAN) ? lcnt[t] : 0;
        if (t < SPAN) lbeg[t] = cc;
        __syncthreads();
        for (int off = 1; off < SPAN; off <<= 1) {
            int v = (t < SPAN && t >= off) ? lbeg[t - off] : 0;
            __syncthreads();
            if (t < SPAN) lbeg[t] += v;
            __syncthreads();
        }
        if (t < SPAN) {
            int excl = lbeg[t] - cc;
            lbeg[t] = excl;
            lcur[t] = excl;
        }
        __syncthreads();
        for (int i = bstart + t; i < bend; i += 1024) {
            int2 r = recs[i];
            int pos = atomicAdd(&lcur[r.x & (SPAN - 1)], 1);
            srec[pos] = r;
        }
        __syncthreads();
        int node = t >> 3;
        int lane = t & 7;
        int beg = lbeg[node];
        int end = beg + lcnt[node];
        float4 acc = make_float4(0.f, 0.f, 0.f, 0.f);
        int i = beg;

        #define GAT1(qq)                                                     \
            float4 v##qq = ((const float4*)(input +                          \
                (size_t)(((unsigned)q##qq.x) >> SPAN_SHIFT) * 32))[lane];    \
            float w##qq = __int_as_float(q##qq.y);
        #define FMA1(qq)                                                     \
            acc.x = fmaf(w##qq, v##qq.x, acc.x);                             \
            acc.y = fmaf(w##qq, v##qq.y, acc.y);                             \
            acc.z = fmaf(w##qq, v##qq.z, acc.z);                             \
            acc.w = fmaf(w##qq, v##qq.w, acc.w);

        // 8-deep main loop (8 outstanding 16B gathers per lane)
        for (; i + 7 < end; i += 8) {
            int2 q0 = srec[i];     int2 q1 = srec[i + 1];
            int2 q2 = srec[i + 2]; int2 q3 = srec[i + 3];
            int2 q4 = srec[i + 4]; int2 q5 = srec[i + 5];
            int2 q6 = srec[i + 6]; int2 q7 = srec[i + 7];
            GAT1(0) GAT1(1) GAT1(2) GAT1(3)
            GAT1(4) GAT1(5) GAT1(6) GAT1(7)
            FMA1(0) FMA1(1) FMA1(2) FMA1(3)
            FMA1(4) FMA1(5) FMA1(6) FMA1(7)
        }
        for (; i + 3 < end; i += 4) {
            int2 q0 = srec[i];     int2 q1 = srec[i + 1];
            int2 q2 = srec[i + 2]; int2 q3 = srec[i + 3];
            GAT1(0) GAT1(1) GAT1(2) GAT1(3)
            FMA1(0) FMA1(1) FMA1(2) FMA1(3)
        }
        for (; i < end; ++i) {
            int2 q0 = srec[i];
            GAT1(0)
            FMA1(0)
        }
        #undef GAT1
        #undef FMA1

        int gnode = base_node + node;
        if (gnode < n_nodes)
            ((float4*)(out + (size_t)gnode * 32))[lane] = acc;
    } else {
        // overflow fallback (correctness only; ~never taken on random data)
        for (int i = t; i < SPAN * 32; i += 1024) {
            int gn = base_node + (i >> 5);
            if (gn < n_nodes) out[(size_t)gn * 32 + (i & 31)] = 0.f;
        }
        __syncthreads();
        for (int i = bstart + t; i < bend; i += 1024) {
            int2 r = recs[i];
            float w = __int_as_float(r.y);
            int s = (int)(((unsigned)r.x) >> SPAN_SHIFT);
            int gn = base_node + (r.x & (SPAN - 1));
            if (gn < n_nodes)
                for (int j = 0; j < 32; ++j)
                    atomicAdd(&out[(size_t)gn * 32 + j], w * input[(size_t)s * 32 + j]);
        }
    }
}

// Last-resort fallback (R3): direct atomic scatter.
__global__ __launch_bounds__(NB) void graphconv_scatter(
    const float* __restrict__ input, const int* __restrict__ sidx,
    const int* __restrict__ tidx, const float* __restrict__ enorm,
    const float* __restrict__ esgn, float* __restrict__ out, int n_edges)
{
    int t = blockIdx.x * NB + threadIdx.x;
    int e = t >> 3;
    int sub = t & 7;
    if (e >= n_edges) return;
    int s = sidx[e];
    int d = tidx[e];
    float w = enorm[e] * esgn[e];
    const float4* src = (const float4*)(input + (size_t)s * 32);
    float4 v = src[sub];
    float* op = out + (size_t)d * 32 + sub * 4;
    atomicAdd(op + 0, v.x * w);
    atomicAdd(op + 1, v.y * w);
    atomicAdd(op + 2, v.z * w);
    atomicAdd(op + 3, v.w * w);
}

extern "C" void kernel_launch(void* const* d_in, const int* in_sizes, int n_in,
                              void* d_out, int out_size, void* d_ws, size_t ws_size,
                              hipStream_t stream) {
    const float* input = (const float*)d_in[0];
    const int*   eidx  = (const int*)d_in[1];   // int64 in reference -> int32 here
    const float* enorm = (const float*)d_in[2];
    const float* esgn  = (const float*)d_in[3];
    float*       out   = (float*)d_out;

    int n_edges = in_sizes[1] / 2;             // eidx is (2, n_edges)
    int n_nodes = in_sizes[0] / 32;            // input is (n_nodes, 32)
    const int* sidx = eidx;
    const int* tidx = eidx + n_edges;

    int K = (n_nodes + SPAN - 1) >> SPAN_SHIFT;   // 782 for 100K nodes

    // Workspace: recs[E int2] | cnt[G*KMAX] | tot[KMAX]
    size_t need = (size_t)n_edges * 8 +
                  ((size_t)G * KMAX + KMAX) * 4;

    if (ws_size >= need && K <= KMAX) {
        int2* recs  = (int2*)d_ws;
        int*  cnt   = (int*)(recs + n_edges);
        int*  tot   = cnt + (size_t)G * KMAX;

        // chunk size: multiple of 4 so vector loads stay 16B-aligned
        int epb = ((n_edges + G - 1) / G + 3) & ~3;
        int vec = ((n_edges & 3) == 0 &&
                   (((uintptr_t)tidx | (uintptr_t)sidx |
                     (uintptr_t)enorm | (uintptr_t)esgn) & 15) == 0) ? 1 : 0;

        hist_kernel   <<<G,    1024, 0, stream>>>(tidx, cnt, n_edges, epb, vec);
        scatter_kernel<<<G,    1024, 0, stream>>>(sidx, tidx, enorm, esgn,
                                                  cnt, tot, recs,
                                                  n_edges, epb, vec);
        bucket_accum  <<<K,    1024, 0, stream>>>(input, recs, tot,
                                                  out, n_nodes);
    } else {
        hipMemsetAsync(d_out, 0, (size_t)out_size * sizeof(float), stream);
        size_t threads_total = (size_t)n_edges * 8;
        int grid = (int)((threads_total + NB - 1) / NB);
        graphconv_scatter<<<grid, NB, 0, stream>>>(input, sidx, tidx, enorm, esgn,
                                                   out, n_edges);
    }
}

// Round 17
// 199.233 us; speedup vs baseline: 1.0473x; 1.0473x over previous
//
#include <hip/hip_runtime.h>

// GraphConv: out[t] += input[s] * (esgn*enorm), 3.2M edges, 100K nodes, D=32 fp32.
// Round 28: R27 split verdict. (a) scan1-fold REGRESSED (scatter 73.9us, total
// +10.5): the per-block row-sum over cnt is a 256-long serial load+add chain
// per thread (~25us), replicated x256 blocks -- folding is only free when the
// folded work is parallel. Reverted. (b) 8-deep accum unroll kept: accum
// dropped out of the top-5 (<72us, was 60.5). This round = R26's verified
// 4-kernel structure + R27's 8-deep unroll only.
// Pipeline: hist -> scan1 -> scatter(+local bscan) -> accum(+local bscan, 8-deep).

#define G    256          // edge chunks / scatter blocks
#define KMAX 1024         // max buckets (span 128 -> n_nodes <= 131072)
#define SPAN_SHIFT 7
#define SPAN 128
#define CAP  6144         // bucket_accum LDS record capacity (48KB)
#define NB   256

// Per-chunk histogram: cnt[g*KMAX + b]. Coalesced matrix write, no atomics
// beyond LDS. (Verified R18.)
__global__ __launch_bounds__(1024) void hist_kernel(
    const int* __restrict__ tidx, int* __restrict__ cnt,
    int n_edges, int epb, int vec)
{
    __shared__ int lh[KMAX];
    int g = blockIdx.x, t = threadIdx.x;
    lh[t] = 0;
    __syncthreads();
    int beg = g * epb;
    int lim = beg + epb; if (lim > n_edges) lim = n_edges;
    if (vec) {
        int nq = (lim > beg) ? ((lim - beg) >> 2) : 0;
        for (int q = t; q < nq; q += 1024) {
            int4 tn = *(const int4*)(tidx + beg + q * 4);
            atomicAdd(&lh[tn.x >> SPAN_SHIFT], 1);
            atomicAdd(&lh[tn.y >> SPAN_SHIFT], 1);
            atomicAdd(&lh[tn.z >> SPAN_SHIFT], 1);
            atomicAdd(&lh[tn.w >> SPAN_SHIFT], 1);
        }
        for (int e = beg + (nq << 2) + t; e < lim; e += 1024)
            atomicAdd(&lh[tidx[e] >> SPAN_SHIFT], 1);
    } else {
        for (int e = beg + t; e < lim; e += 1024)
            atomicAdd(&lh[tidx[e] >> SPAN_SHIFT], 1);
    }
    __syncthreads();
    cnt[g * KMAX + t] = lh[t];
}

// Per-bucket exclusive scan over the G chunk counts -> pref[g][b], tot[b].
// (Verified R18.)
__global__ __launch_bounds__(G) void scan1_kernel(
    const int* __restrict__ cnt, int* __restrict__ pref, int* __restrict__ tot)
{
    __shared__ int part[G];
    int b = blockIdx.x, t = threadIdx.x;
    int c = cnt[t * KMAX + b];
    part[t] = c;
    __syncthreads();
    for (int off = 1; off < G; off <<= 1) {
        int v = (t >= off) ? part[t - off] : 0;
        __syncthreads();
        part[t] += v;
        __syncthreads();
    }
    pref[t * KMAX + b] = part[t] - c;
    if (t == G - 1) tot[b] = part[t];
}

// Deterministic scatter: block g owns chunk g; position = gbase[b] + LDS rank.
// R26 form: bucket-base scan computed locally from tot (parallel LDS scan).
__global__ __launch_bounds__(1024) void scatter_kernel(
    const int* __restrict__ sidx, const int* __restrict__ tidx,
    const float* __restrict__ enorm, const float* __restrict__ esgn,
    const int* __restrict__ tot, const int* __restrict__ pref,
    int2* __restrict__ recs, int n_edges, int epb, int vec)
{
    __shared__ int gbase[KMAX];
    __shared__ int lh[KMAX];
    __shared__ int part[KMAX];
    int g = blockIdx.x, t = threadIdx.x;

    // local exclusive scan of tot -> bucket bases
    int c = tot[t];
    part[t] = c;
    __syncthreads();
    for (int off = 1; off < KMAX; off <<= 1) {
        int v = (t >= off) ? part[t - off] : 0;
        __syncthreads();
        part[t] += v;
        __syncthreads();
    }
    gbase[t] = (part[t] - c) + pref[g * KMAX + t];
    lh[t] = 0;
    __syncthreads();

    int beg = g * epb;
    int lim = beg + epb; if (lim > n_edges) lim = n_edges;

    #define SCAT_EDGE(tn_, sn_, w_) {                                        \
        int b_ = (tn_) >> SPAN_SHIFT;                                        \
        int rank_ = atomicAdd(&lh[b_], 1);                                   \
        unsigned rec_ = ((unsigned)(sn_) << SPAN_SHIFT) |                    \
                        (unsigned)((tn_) & (SPAN - 1));                      \
        recs[gbase[b_] + rank_] = make_int2((int)rec_, __float_as_int(w_)); }

    if (vec) {
        int nq = (lim > beg) ? ((lim - beg) >> 2) : 0;
        for (int q = t; q < nq; q += 1024) {
            int e = beg + q * 4;
            int4   tn = *(const int4*)(tidx + e);
            int4   sn = *(const int4*)(sidx + e);
            float4 nw = *(const float4*)(enorm + e);
            float4 sw = *(const float4*)(esgn + e);
            SCAT_EDGE(tn.x, sn.x, nw.x * sw.x);
            SCAT_EDGE(tn.y, sn.y, nw.y * sw.y);
            SCAT_EDGE(tn.z, sn.z, nw.z * sw.z);
            SCAT_EDGE(tn.w, sn.w, nw.w * sw.w);
        }
        for (int e = beg + (nq << 2) + t; e < lim; e += 1024) {
            int tn = tidx[e]; int sn = sidx[e];
            float w = enorm[e] * esgn[e];
            SCAT_EDGE(tn, sn, w);
        }
    } else {
        for (int e = beg + t; e < lim; e += 1024) {
            int tn = tidx[e]; int sn = sidx[e];
            float w = enorm[e] * esgn[e];
            SCAT_EDGE(tn, sn, w);
        }
    }
    #undef SCAT_EDGE
}

// Fused node-sort + accumulate, one block per bucket (128 nodes).
// R26 scan prologue + R27 8-deep gather unroll (kept: accum left top-5).
__global__ __launch_bounds__(1024) void bucket_accum(
    const float* __restrict__ input, const int2* __restrict__ recs,
    const int* __restrict__ tot, float* __restrict__ out, int n_nodes)
{
    __shared__ int2 srec[CAP];             // 48 KB
    __shared__ int part[KMAX];             // 4 KB (scan prologue)
    __shared__ int lcnt[SPAN];
    __shared__ int lbeg[SPAN];
    __shared__ int lcur[SPAN];
    __shared__ int sb[2];
    int b = blockIdx.x;
    int t = threadIdx.x;

    // local exclusive scan of tot -> this bucket's [bstart, bend)
    int c = tot[t];
    part[t] = c;
    __syncthreads();
    for (int off = 1; off < KMAX; off <<= 1) {
        int v = (t >= off) ? part[t - off] : 0;
        __syncthreads();
        part[t] += v;
        __syncthreads();
    }
    if (t == b) { sb[0] = part[t] - c; sb[1] = part[t]; }
    __syncthreads();
    int bstart = sb[0], bend = sb[1];
    int base_node = b << SPAN_SHIFT;

    if (bend - bstart <= CAP) {
        if (t < SPAN) lcnt[t] = 0;
        __syncthreads();
        for (int i = bstart + t; i < bend; i += 1024)
            atomicAdd(&lcnt[recs[i].x & (SPAN - 1)], 1);
        __syncthreads();
        int cc = (t < SPAN) ? lcnt[t] : 0;
        if (t < SPAN) lbeg[t] = cc;
        __syncthreads();
        for (int off = 1; off < SPAN; off <<= 1) {
            int v = (t < SPAN && t >= off) ? lbeg[t - off] : 0;
            __syncthreads();
            if (t < SPAN) lbeg[t] += v;
            __syncthreads();
        }
        if (t < SPAN) {
            int excl = lbeg[t] - cc;
            lbeg[t] = excl;
            lcur[t] = excl;
        }
        __syncthreads();
        for (int i = bstart + t; i < bend; i += 1024) {
            int2 r = recs[i];
            int pos = atomicAdd(&lcur[r.x & (SPAN - 1)], 1);
            srec[pos] = r;
        }
        __syncthreads();
        int node = t >> 3;
        int lane = t & 7;
        int beg = lbeg[node];
        int end = beg + lcnt[node];
        float4 acc = make_float4(0.f, 0.f, 0.f, 0.f);
        int i = beg;

        #define GAT1(qq)                                                     \
            float4 v##qq = ((const float4*)(input +                          \
                (size_t)(((unsigned)q##qq.x) >> SPAN_SHIFT) * 32))[lane];    \
            float w##qq = __int_as_float(q##qq.y);
        #define FMA1(qq)                                                     \
            acc.x = fmaf(w##qq, v##qq.x, acc.x);                             \
            acc.y = fmaf(w##qq, v##qq.y, acc.y);                             \
            acc.z = fmaf(w##qq, v##qq.z, acc.z);                             \
            acc.w = fmaf(w##qq, v##qq.w, acc.w);

        // 8-deep main loop (8 outstanding 16B gathers per lane)
        for (; i + 7 < end; i += 8) {
            int2 q0 = srec[i];     int2 q1 = srec[i + 1];
            int2 q2 = srec[i + 2]; int2 q3 = srec[i + 3];
            int2 q4 = srec[i + 4]; int2 q5 = srec[i + 5];
            int2 q6 = srec[i + 6]; int2 q7 = srec[i + 7];
            GAT1(0) GAT1(1) GAT1(2) GAT1(3)
            GAT1(4) GAT1(5) GAT1(6) GAT1(7)
            FMA1(0) FMA1(1) FMA1(2) FMA1(3)
            FMA1(4) FMA1(5) FMA1(6) FMA1(7)
        }
        for (; i + 3 < end; i += 4) {
            int2 q0 = srec[i];     int2 q1 = srec[i + 1];
            int2 q2 = srec[i + 2]; int2 q3 = srec[i + 3];
            GAT1(0) GAT1(1) GAT1(2) GAT1(3)
            FMA1(0) FMA1(1) FMA1(2) FMA1(3)
        }
        for (; i < end; ++i) {
            int2 q0 = srec[i];
            GAT1(0)
            FMA1(0)
        }
        #undef GAT1
        #undef FMA1

        int gnode = base_node + node;
        if (gnode < n_nodes)
            ((float4*)(out + (size_t)gnode * 32))[lane] = acc;
    } else {
        // overflow fallback (correctness only; ~never taken on random data)
        for (int i = t; i < SPAN * 32; i += 1024) {
            int gn = base_node + (i >> 5);
            if (gn < n_nodes) out[(size_t)gn * 32 + (i & 31)] = 0.f;
        }
        __syncthreads();
        for (int i = bstart + t; i < bend; i += 1024) {
            int2 r = recs[i];
            float w = __int_as_float(r.y);
            int s = (int)(((unsigned)r.x) >> SPAN_SHIFT);
            int gn = base_node + (r.x & (SPAN - 1));
            if (gn < n_nodes)
                for (int j = 0; j < 32; ++j)
                    atomicAdd(&out[(size_t)gn * 32 + j], w * input[(size_t)s * 32 + j]);
        }
    }
}

// Last-resort fallback (R3): direct atomic scatter.
__global__ __launch_bounds__(NB) void graphconv_scatter(
    const float* __restrict__ input, const int* __restrict__ sidx,
    const int* __restrict__ tidx, const float* __restrict__ enorm,
    const float* __restrict__ esgn, float* __restrict__ out, int n_edges)
{
    int t = blockIdx.x * NB + threadIdx.x;
    int e = t >> 3;
    int sub = t & 7;
    if (e >= n_edges) return;
    int s = sidx[e];
    int d = tidx[e];
    float w = enorm[e] * esgn[e];
    const float4* src = (const float4*)(input + (size_t)s * 32);
    float4 v = src[sub];
    float* op = out + (size_t)d * 32 + sub * 4;
    atomicAdd(op + 0, v.x * w);
    atomicAdd(op + 1, v.y * w);
    atomicAdd(op + 2, v.z * w);
    atomicAdd(op + 3, v.w * w);
}

extern "C" void kernel_launch(void* const* d_in, const int* in_sizes, int n_in,
                              void* d_out, int out_size, void* d_ws, size_t ws_size,
                              hipStream_t stream) {
    const float* input = (const float*)d_in[0];
    const int*   eidx  = (const int*)d_in[1];   // int64 in reference -> int32 here
    const float* enorm = (const float*)d_in[2];
    const float* esgn  = (const float*)d_in[3];
    float*       out   = (float*)d_out;

    int n_edges = in_sizes[1] / 2;             // eidx is (2, n_edges)
    int n_nodes = in_sizes[0] / 32;            // input is (n_nodes, 32)
    const int* sidx = eidx;
    const int* tidx = eidx + n_edges;

    int K = (n_nodes + SPAN - 1) >> SPAN_SHIFT;   // 782 for 100K nodes

    // Workspace: recs[E int2] | cnt[G*KMAX] | pref[G*KMAX] | tot[KMAX]
    size_t need = (size_t)n_edges * 8 +
                  ((size_t)2 * G * KMAX + KMAX) * 4;

    if (ws_size >= need && K <= KMAX) {
        int2* recs  = (int2*)d_ws;
        int*  cnt   = (int*)(recs + n_edges);
        int*  pref  = cnt + (size_t)G * KMAX;
        int*  tot   = pref + (size_t)G * KMAX;

        // chunk size: multiple of 4 so vector loads stay 16B-aligned
        int epb = ((n_edges + G - 1) / G + 3) & ~3;
        int vec = ((n_edges & 3) == 0 &&
                   (((uintptr_t)tidx | (uintptr_t)sidx |
                     (uintptr_t)enorm | (uintptr_t)esgn) & 15) == 0) ? 1 : 0;

        hist_kernel   <<<G,    1024, 0, stream>>>(tidx, cnt, n_edges, epb, vec);
        scan1_kernel  <<<KMAX, G,    0, stream>>>(cnt, pref, tot);
        scatter_kernel<<<G,    1024, 0, stream>>>(sidx, tidx, enorm, esgn,
                                                  tot, pref, recs,
                                                  n_edges, epb, vec);
        bucket_accum  <<<K,    1024, 0, stream>>>(input, recs, tot,
                                                  out, n_nodes);
    } else {
        hipMemsetAsync(d_out, 0, (size_t)out_size * sizeof(float), stream);
        size_t threads_total = (size_t)n_edges * 8;
        int grid = (int)((threads_total + NB - 1) / NB);
        graphconv_scatter<<<grid, NB, 0, stream>>>(input, sidx, tidx, enorm, esgn,
                                                   out, n_edges);
    }
}